// Round 8
// baseline (460.725 us; speedup 1.0000x reference)
//
#include <hip/hip_runtime.h>
#include <hip/hip_bf16.h>

#define NN    38000
#define HID   128
#define RR    8
#define EE    200000
#define NROWS 60000
#define FF    19
#define NCLS  10
#define NRD   (RR*NN)         // 304000
#define HB    38912           // 1024*38, padded bin count (>= NN)
#define CH    16              // chunks per relation
#define CE    (EE/CH)         // 12500 edges per chunk

typedef __hip_bfloat16 bf16;
typedef __attribute__((ext_vector_type(8))) short short8;
typedef __attribute__((ext_vector_type(4))) float floatx4;

__device__ __forceinline__ float b2f(bf16 x){ return __bfloat162float(x); }
__device__ __forceinline__ bf16  f2b(float x){ return __float2bfloat16(x); }

__device__ __forceinline__ int geti(const void* a, long long i, int wide){
  return wide ? (int)(((const long long*)a)[i]) : ((const int*)a)[i];
}

__global__ void k_fill(float* out, int n, float v){
  int i = blockIdx.x*256 + threadIdx.x;
  if (i < n) out[i] = v;
}

// r12's proven parallel sniff (1 wave)
__global__ void k_sniff(const void* mask, const void* ridx, const void* esrc, int* flags){
  int lane = threadIdx.x;    // blockDim = 64
  const unsigned short* mu = (const unsigned short*)mask;
  int l3f80e=0, l3f80o=0, lbytehi=0, loddnz=0, lother=0;
  for (int i = lane; i < 4096; i += 64){
    unsigned v = mu[i];
    if (v == 0) continue;
    if (v == 0x3F80){ if (i & 1) l3f80o = 1; else l3f80e = 1; continue; }
    unsigned lo = v & 0xFF, hi = v >> 8;
    int lob = (lo == 0 || lo == 1 || lo == 0xFF);
    int hib = (hi == 0 || hi == 1 || hi == 0xFF);
    if (lob && hib){ if (hi) lbytehi = 1; if (i & 1) loddnz = 1; continue; }
    lother = 1;
  }
  int a3f80e = __any(l3f80e);
  int a3f80o = __any(l3f80o);
  int abytehi = __any(lbytehi);
  int aoddnz = __any(loddnz);
  int aother = __any(lother);
  int mtype = -1;
  if (!aother){
    if (a3f80e && !abytehi && !aoddnz)       mtype = 2;
    else if (a3f80o && !a3f80e && !abytehi)  mtype = 3;
    else if (!a3f80e && !a3f80o){
      if (abytehi || aoddnz) mtype = 1;
      else                   mtype = 0;     // int32 0/1 (actual runtime case)
    }
  }
  const int* es = (const int*)esrc;
  int loddE = 0, lseenE = 0;
  for (int i = lane; i < 512; i += 64){
    if (es[2*i+1] != 0) loddE = 1;
    if (es[2*i] > 1)    lseenE = 1;
  }
  int fE = (!__any(loddE) && __any(lseenE)) ? 1 : 0;
  const int* ri = (const int*)ridx;
  int loddI = 0, lseenI = 0;
  for (int i = lane; i < 512; i += 64){
    if (ri[2*i+1] != 0) loddI = 1;
    if (ri[2*i] > 1)    lseenI = 1;
  }
  int fI = (!__any(loddI) && __any(lseenI)) ? 1 : 0;
  if (lane == 0){ flags[1] = mtype; flags[3] = fE; flags[4] = fI; }
}

// ---- LDS-histogram graph prep ----

// 256 blocks: blocks 0-127 histogram dst (8 rel x 16 chunks), 128-255 histogram src.
__global__ __launch_bounds__(1024) void kg_hist(const void* esrc, const void* edst,
                                                int* __restrict__ ghd, int* __restrict__ ghs,
                                                const int* flags){
  __shared__ int hist[HB];
  int t = threadIdx.x;
  for (int i = t; i < HB; i += 1024) hist[i] = 0;
  __syncthreads();
  int b = blockIdx.x;
  int side = b >> 7;                 // 0: dst, 1: src
  int r = (b >> 4) & 7, c = b & 15;
  int wide = flags[3];
  const void* e = side ? esrc : edst;
  long long base = (long long)r*EE + (long long)c*CE;
  if (!wide){
    const int* p = (const int*)e + base;
    for (int i = t; i < CE; i += 1024) atomicAdd(&hist[p[i]], 1);
  } else {
    const long long* p = (const long long*)e + base;
    for (int i = t; i < CE; i += 1024) atomicAdd(&hist[(int)p[i]], 1);
  }
  __syncthreads();
  int* out = (side ? ghs : ghd) + (long long)(r*CH + c)*HB;
  for (int i = t; i < HB; i += 1024) out[i] = hist[i];
}

// wide reduce: per-relation dst totals + ns = rsqrt(outdeg) (folds k_norm)
__global__ void kg_tot(const int* __restrict__ ghd, const int* __restrict__ ghs,
                       int* __restrict__ totg, float* __restrict__ ns){
  int i = blockIdx.x*256 + threadIdx.x;   // over RR*HB
  if (i >= RR*HB) return;
  int r = i / HB, bin = i - r*HB;
  int sd = 0, ss = 0;
#pragma unroll
  for (int c = 0; c < CH; c++){
    sd += ghd[(long long)(r*CH+c)*HB + bin];
    ss += ghs[(long long)(r*CH+c)*HB + bin];
  }
  totg[i] = sd;
  if (bin < NN) ns[r*NN + bin] = rsqrtf((float)(ss > 0 ? ss : 1));
}

// per-relation exclusive scan of 38912 bins, fully in LDS -> rowptr
__global__ __launch_bounds__(1024) void kg_scan(const int* __restrict__ totg,
                                                int* __restrict__ rowptr){
  __shared__ int tot[HB];
  __shared__ int wsum[16];
  int t = threadIdx.x, r = blockIdx.x;
  for (int i = t; i < HB; i += 1024) tot[i] = totg[r*HB + i];
  __syncthreads();
  int b0 = t*38;
  int loc[38], s = 0;
#pragma unroll
  for (int j = 0; j < 38; j++){ loc[j] = s; s += tot[b0+j]; }
  int lane = t & 63, w = t >> 6;
  int sc = s;
  for (int off = 1; off < 64; off <<= 1){
    int v = __shfl_up(sc, off);
    if (lane >= off) sc += v;
  }
  if (lane == 63) wsum[w] = sc;
  __syncthreads();
  if (t < 16){
    int v = wsum[t];
    int scw = v;
    for (int off = 1; off < 16; off <<= 1){
      int u = __shfl_up(scw, off);
      if (t >= off) scw += u;
    }
    wsum[t] = scw - v;     // exclusive cross-wave offset
  }
  __syncthreads();
  int base = r*EE + (sc - s) + wsum[w];   // relation base + exclusive prefix
#pragma unroll
  for (int j = 0; j < 38; j++) tot[b0+j] = base + loc[j];
  __syncthreads();
  for (int i = t; i < NN; i += 1024) rowptr[r*NN + i] = tot[i];
  if (r == RR-1 && t == 0) rowptr[NRD] = RR*EE;
}

// wide: per-chunk cursor bases = rowptr + prefix over chunk histograms
__global__ void kg_curs(const int* __restrict__ ghd, const int* __restrict__ rowptr,
                        int* __restrict__ gcurs){
  int i = blockIdx.x*256 + threadIdx.x;   // over RR*NN
  if (i >= NRD) return;
  int r = i / NN, bin = i - r*NN;
  int p = rowptr[i];
#pragma unroll
  for (int c = 0; c < CH; c++){
    gcurs[(long long)(r*CH+c)*HB + bin] = p;
    p += ghd[(long long)(r*CH+c)*HB + bin];
  }
}

// 128 blocks (8 rel x 16 chunks): LDS cursors, zero global atomics.
// Emits csrw = interleaved (src, ns[src]) 8B pairs so k_layer streams one array.
__global__ __launch_bounds__(1024) void kg_scatter(const void* esrc, const void* edst,
                                                   const int* __restrict__ gcurs,
                                                   const float* __restrict__ ns,
                                                   int2* __restrict__ csrw, const int* flags){
  __shared__ int cur[HB];
  int t = threadIdx.x, b = blockIdx.x;
  int r = b >> 4, c = b & 15;
  const int* g = gcurs + (long long)(r*CH + c)*HB;
  for (int i = t; i < HB; i += 1024) cur[i] = g[i];
  __syncthreads();
  if (b == 0 && t < 8){ int2 z; z.x = 0; z.y = 0; csrw[RR*EE + t] = z; }  // zero pad
  int wide = flags[3];
  const float* nsr = ns + r*NN;
  long long base = (long long)r*EE + (long long)c*CE;
  if (!wide){
    const int* ps = (const int*)esrc + base;
    const int* pd = (const int*)edst + base;
    for (int i = t; i < CE; i += 1024){
      int d = pd[i], s = ps[i];
      int pos = atomicAdd(&cur[d], 1);
      int2 v; v.x = s; v.y = __float_as_int(nsr[s]);
      csrw[pos] = v;
    }
  } else {
    const long long* ps = (const long long*)esrc + base;
    const long long* pd = (const long long*)edst + base;
    for (int i = t; i < CE; i += 1024){
      int d = (int)pd[i], s = (int)ps[i];
      int pos = atomicAdd(&cur[d], 1);
      int2 v; v.x = s; v.y = __float_as_int(nsr[s]);
      csrw[pos] = v;
    }
  }
}

// ---- end graph prep ----

__global__ void k_bias(const float* b_in, const float* b1, const float* b2,
                       const float* bm1, const float* bm2, const float* bm3, float* o){
  int t = threadIdx.x;
  o[t] = b_in[t];
  float s1 = 0.f, s2 = 0.f;
  for (int r = 0; r < RR; r++){ s1 += b1[r*HID+t]; s2 += b2[r*HID+t]; }
  o[128+t] = s1; o[256+t] = s2;
  o[384+t] = bm1[t]; o[512+t] = bm2[t];
  if (t < NCLS) o[640+t] = bm3[t];
}

// one pack kernel: [8][128][128] W1,W2 stacks (K=512 frag order) + Wm1,Wm2 (K=128)
__global__ void k_packall(const float* __restrict__ W1, const float* __restrict__ W2,
                          const float* __restrict__ Wm1, const float* __restrict__ Wm2,
                          bf16* __restrict__ W1p, bf16* __restrict__ W2p,
                          bf16* __restrict__ Wm1p, bf16* __restrict__ Wm2p){
  int idx0 = blockIdx.x*256 + threadIdx.x;
  if (idx0 < 4*65536){
    const float* W = (idx0 < 2*65536) ? W1 : W2;
    bf16* out      = (idx0 < 2*65536) ? W1p : W2p;
    int idx = idx0 & (2*65536 - 1);
    int j = idx & 7;
    int l = (idx >> 3) & 63;
    int t = (idx >> 9) & 127;
    int g = idx >> 16;
    int ktg = t & 15, nt = t >> 4;
    int kglob = ktg*32 + ((l>>4)<<3) + j;
    int rel = kglob >> 7;
    int krow = kglob & 127;
    int n = nt*16 + (l&15);
    out[idx] = f2b(W[((g*4 + rel)*128 + krow)*128 + n]);
  } else if (idx0 < 4*65536 + 2*16384){
    int t2 = idx0 - 4*65536;
    const float* B = (t2 < 16384) ? Wm1 : Wm2;
    bf16* out      = (t2 < 16384) ? Wm1p : Wm2p;
    int idx = t2 & 16383;
    int j  = idx & 7;
    int l  = (idx >> 3) & 63;
    int t  = idx >> 9;          // 0..31
    int kt = t & 3;             // KT=4
    int nt = t >> 2;
    int k = kt*32 + ((l>>4)<<3) + j;
    int n = nt*16 + (l&15);
    out[idx] = f2b(B[k*128 + n]);
  }
}

// input linear + relu (f32 VALU, K=64) -> h1 bf16  [r13-r15 proven, restored]
__global__ void k_gemm_in(const float* __restrict__ A, const float* __restrict__ B,
                          const float* bias, bf16* __restrict__ out){
  int row0 = blockIdx.x * 4;
  int col = threadIdx.x;
  float a0=0.f, a1=0.f, a2=0.f, a3=0.f;
  for (int k = 0; k < 64; k++){
    float bv = B[k*HID + col];
    a0 += A[(long long)(row0+0)*64 + k] * bv;
    a1 += A[(long long)(row0+1)*64 + k] * bv;
    a2 += A[(long long)(row0+2)*64 + k] * bv;
    a3 += A[(long long)(row0+3)*64 + k] * bv;
  }
  float bb = bias[col];
  out[(long long)(row0+0)*HID + col] = f2b(fmaxf(a0 + bb, 0.f));
  out[(long long)(row0+1)*HID + col] = f2b(fmaxf(a1 + bb, 0.f));
  out[(long long)(row0+2)*HID + col] = f2b(fmaxf(a2 + bb, 0.f));
  out[(long long)(row0+3)*HID + col] = f2b(fmaxf(a3 + bb, 0.f));
}

// ---- k_layer: fused agg + MFMA, row-pipelined phase 1 ----
// Per row i: row i's 8 gathers are already in flight (issued last iteration);
// issue row i+1's s_load window + gathers, THEN accumulate row i. Two named
// register sets alternate through a fully-unrolled 16-row loop (static indexing).
#define LOADW(Q, base_) \
  Q##0 = cw[(base_)+0]; Q##1 = cw[(base_)+1]; Q##2 = cw[(base_)+2]; Q##3 = cw[(base_)+3]; \
  Q##4 = cw[(base_)+4]; Q##5 = cw[(base_)+5]; Q##6 = cw[(base_)+6]; Q##7 = cw[(base_)+7];

#define GATHW(P, Q) \
  P##0 = hv[(long long)(int)Q##0*64 + lane]; \
  P##1 = hv[(long long)(int)Q##1*64 + lane]; \
  P##2 = hv[(long long)(int)Q##2*64 + lane]; \
  P##3 = hv[(long long)(int)Q##3*64 + lane]; \
  P##4 = hv[(long long)(int)Q##4*64 + lane]; \
  P##5 = hv[(long long)(int)Q##5*64 + lane]; \
  P##6 = hv[(long long)(int)Q##6*64 + lane]; \
  P##7 = hv[(long long)(int)Q##7*64 + lane];

#define ACCE(Qv, Pv, cond) { \
  float wk_ = (cond) ? __int_as_float((int)((Qv) >> 32)) : 0.f; \
  acc0 += wk_ * __uint_as_float((Pv) << 16); \
  acc1 += wk_ * __uint_as_float((Pv) & 0xffff0000u); }

#define ROWBODY(i, QC, PC, QN, PN) { \
  int b_ = __builtin_amdgcn_readfirstlane(__shfl(rp, (i))); \
  int e_ = __builtin_amdgcn_readfirstlane(__shfl(rp, (i)+1)); \
  LOADW(QN, e_)                       /* next row's window (begin = e_) */ \
  GATHW(PN, QN)                       /* issue next row's gathers */ \
  float acc0 = 0.f, acc1 = 0.f; \
  ACCE(QC##0, PC##0, b_+0 < e_) \
  ACCE(QC##1, PC##1, b_+1 < e_) \
  ACCE(QC##2, PC##2, b_+2 < e_) \
  ACCE(QC##3, PC##3, b_+3 < e_) \
  ACCE(QC##4, PC##4, b_+4 < e_) \
  ACCE(QC##5, PC##5, b_+5 < e_) \
  ACCE(QC##6, PC##6, b_+6 < e_) \
  ACCE(QC##7, PC##7, b_+7 < e_) \
  for (int j = b_ + 8; j < e_; j += 8){      /* slow path: deg > 8 (~9% rows) */ \
    unsigned long long q0 = cw[j],   q1 = cw[j+1], q2 = cw[j+2], q3 = cw[j+3]; \
    unsigned long long q4 = cw[j+4], q5 = cw[j+5], q6 = cw[j+6], q7 = cw[j+7]; \
    unsigned p0 = hv[(long long)(int)q0*64 + lane]; \
    unsigned p1 = hv[(long long)(int)q1*64 + lane]; \
    unsigned p2 = hv[(long long)(int)q2*64 + lane]; \
    unsigned p3 = hv[(long long)(int)q3*64 + lane]; \
    unsigned p4 = hv[(long long)(int)q4*64 + lane]; \
    unsigned p5 = hv[(long long)(int)q5*64 + lane]; \
    unsigned p6 = hv[(long long)(int)q6*64 + lane]; \
    unsigned p7 = hv[(long long)(int)q7*64 + lane]; \
    ACCE(q0, p0, 1) \
    ACCE(q1, p1, j+1 < e_) \
    ACCE(q2, p2, j+2 < e_) \
    ACCE(q3, p3, j+3 < e_) \
    ACCE(q4, p4, j+4 < e_) \
    ACCE(q5, p5, j+5 < e_) \
    ACCE(q6, p6, j+6 < e_) \
    ACCE(q7, p7, j+7 < e_) \
  } \
  int deg = e_ - b_; \
  float nd = rsqrtf((float)(deg > 0 ? deg : 1)); \
  bf16 o0 = f2b(acc0 * nd), o1 = f2b(acc1 * nd); \
  unsigned ov = ((unsigned)(*(unsigned short*)&o1) << 16) | (*(unsigned short*)&o0); \
  int addr = (w << 12) + ((i) << 8) + (lane << 2); \
  addr ^= (((i) & 7) << 4); \
  *(unsigned*)(lds + addr) = ov; }

__global__ __launch_bounds__(512) void k_layer(const bf16* __restrict__ h,
                                               const int* __restrict__ rowptr,
                                               const unsigned long long* __restrict__ cw,
                                               const bf16* __restrict__ Bp,
                                               const float* __restrict__ bias,
                                               bf16* __restrict__ hout, int relu){
  __shared__ char lds[8*16*256];     // 8 relation tiles of [16 rows][128 bf16], swizzled
  int w = threadIdx.x >> 6;          // wave id = relation
  int lane = threadIdx.x & 63;
  int d0 = blockIdx.x << 4;
  const unsigned* hv = (const unsigned*)h;

  // 17 row boundaries, one coalesced read
  int rp = 0;
  if (lane < 17) rp = rowptr[w*NN + d0 + lane];

  unsigned long long qa0,qa1,qa2,qa3,qa4,qa5,qa6,qa7;
  unsigned long long qb0,qb1,qb2,qb3,qb4,qb5,qb6,qb7;
  unsigned pa0,pa1,pa2,pa3,pa4,pa5,pa6,pa7;
  unsigned pb0,pb1,pb2,pb3,pb4,pb5,pb6,pb7;

  // prologue: row 0's window + gathers
  {
    int b0_ = __builtin_amdgcn_readfirstlane(__shfl(rp, 0));
    LOADW(qa, b0_)
    GATHW(pa, qa)
  }
  ROWBODY( 0, qa, pa, qb, pb)
  ROWBODY( 1, qb, pb, qa, pa)
  ROWBODY( 2, qa, pa, qb, pb)
  ROWBODY( 3, qb, pb, qa, pa)
  ROWBODY( 4, qa, pa, qb, pb)
  ROWBODY( 5, qb, pb, qa, pa)
  ROWBODY( 6, qa, pa, qb, pb)
  ROWBODY( 7, qb, pb, qa, pa)
  ROWBODY( 8, qa, pa, qb, pb)
  ROWBODY( 9, qb, pb, qa, pa)
  ROWBODY(10, qa, pa, qb, pb)
  ROWBODY(11, qb, pb, qa, pa)
  ROWBODY(12, qa, pa, qb, pb)
  ROWBODY(13, qb, pb, qa, pa)
  ROWBODY(14, qa, pa, qb, pb)
  ROWBODY(15, qb, pb, qa, pa)
  __syncthreads();

  // phase 2: K=1024 MFMA, wave w -> output cols [16w, 16w+16)
  floatx4 acc = (floatx4){0.f,0.f,0.f,0.f};
  int row = lane & 15;
  int kb = (lane >> 4) << 4;                      // (lane>>4)*8 elems * 2B
#pragma unroll
  for (int rel = 0; rel < 8; rel++){
    int half = rel >> 2;
    const bf16* bp = Bp + half*65536 + lane*8 + (w*16 + (rel & 3)*4)*512;
#pragma unroll
    for (int ktl = 0; ktl < 4; ktl++){
      // full unswizzled offset FIRST, then XOR (r3 carry-through-swizzle fix)
      int off = (row << 8) + ktl*64 + kb;
      off ^= ((row & 7) << 4);
      short8 a = *(const short8*)(lds + (rel << 12) + off);
      short8 b = *(const short8*)(bp + ktl*512);
      acc = __builtin_amdgcn_mfma_f32_16x16x32_bf16(a, b, acc, 0, 0, 0);
    }
  }
  int col = w*16 + (lane & 15);
  int row0 = d0 + ((lane >> 4) << 2);
  float bb = bias[col];
#pragma unroll
  for (int v = 0; v < 4; v++){
    float x = acc[v] + bb;
    if (relu) x = fmaxf(x, 0.f);
    hout[(long long)(row0 + v)*HID + col] = f2b(x);
  }
}

// K=128 MFMA + relu epilogue (r13-proven layout)
__global__ void k_mfma_out(const bf16* __restrict__ A, const bf16* __restrict__ Bp,
                           const float* __restrict__ bias, bf16* __restrict__ out, int M){
  int wave = (blockIdx.x*blockDim.x + threadIdx.x) >> 6;
  int lane = threadIdx.x & 63;
  int rowBase = wave << 4;
  if (rowBase >= M) return;
  long long aRow = rowBase + (lane & 15);
  int kGrp = (lane >> 4) << 3;
  floatx4 acc[8];
#pragma unroll
  for (int nt = 0; nt < 8; nt++) acc[nt] = (floatx4){0.f,0.f,0.f,0.f};
  const bf16* bp = Bp + lane*8;
#pragma unroll
  for (int kt = 0; kt < 4; kt++){
    short8 a = *(const short8*)(A + aRow*HID + kt*32 + kGrp);
#pragma unroll
    for (int nt = 0; nt < 8; nt++){
      short8 b = *(const short8*)(bp + (nt*4 + kt)*512);
      acc[nt] = __builtin_amdgcn_mfma_f32_16x16x32_bf16(a, b, acc[nt], 0, 0, 0);
    }
  }
  int colB = lane & 15;
  int rowQ = rowBase + ((lane >> 4) << 2);
#pragma unroll
  for (int nt = 0; nt < 8; nt++){
    int col = nt*16 + colB;
    float bb = bias[col];
#pragma unroll
    for (int v = 0; v < 4; v++)
      out[(long long)(rowQ+v)*HID + col] = f2b(fmaxf(acc[nt][v] + bb, 0.f));
  }
}

// masked mean; 4 waves/block, 1 wave/row; ballot + shfl-broadcast indices,
// fully unrolled 19 unconditional gathers (r2-proven ILP form).
__global__ void k_mean(const bf16* __restrict__ h, const void* ridx, const void* rmask,
                       const int* flags, bf16* __restrict__ mean){
  int row = blockIdx.x*4 + (threadIdx.x >> 6);
  int lane = threadIdx.x & 63;
  int mt = flags[1];
  int wide = flags[4];
  const int* m4            = (const int*)rmask;
  const unsigned char* m1  = (const unsigned char*)rmask;
  const unsigned short* m2 = (const unsigned short*)rmask;
  const unsigned int* mw   = (const unsigned int*)rmask;
  const unsigned* hv = (const unsigned*)h;
  int on = 0, idxl = 0;
  if (lane < FF){
    long long i = (long long)row*FF + lane;
    if      (mt == 1) on = (m1[i] != 0);
    else if (mt == 2) on = (m2[i] != 0);
    else if (mt == 3) on = (mw[i] != 0);
    else              on = (m4[i] != 0);
    if (on) idxl = geti(ridx, i, wide);
  }
  unsigned long long bal = __ballot(on);
  float cnt = (float)__popcll(bal);
  float acc0 = 0.f, acc1 = 0.f;
#pragma unroll
  for (int j = 0; j < FF; j++){
    int s = __shfl(idxl, j);                       // 0 when masked off -> row 0 (L1-hot)
    float w = (float)((bal >> j) & 1ull);
    unsigned pv = hv[(long long)s*64 + lane];
    acc0 += w * __uint_as_float(pv << 16);
    acc1 += w * __uint_as_float(pv & 0xffff0000u);
  }
  float inv = 1.f / fmaxf(cnt, 1.f);
  bf16 o0 = f2b(acc0 * inv), o1 = f2b(acc1 * inv);
  unsigned ov = ((unsigned)(*(unsigned short*)&o1) << 16) | (*(unsigned short*)&o0);
  ((unsigned*)mean)[(long long)row*64 + lane] = ov;
}

// final layer: out(f32)[NROWS][10]
__global__ void k_last(const bf16* __restrict__ A, const float* __restrict__ B,
                       const float* bias, float* __restrict__ out){
  int i = blockIdx.x*256 + threadIdx.x;
  if (i >= NROWS*NCLS) return;
  int row = i / NCLS, col = i - row*NCLS;
  float acc = bias[col];
  const bf16* ar = A + (long long)row*HID;
  for (int k = 0; k < HID; k++) acc += b2f(ar[k]) * B[k*NCLS + col];
  out[i] = acc;
}

extern "C" void kernel_launch(void* const* d_in, const int* in_sizes, int n_in,
                              void* d_out, int out_size, void* d_ws, size_t ws_size,
                              hipStream_t stream){
  float* out = (float*)d_out;

  static const int expect[17] = {
    NN*64, RR*EE, RR*EE, NROWS*FF, NROWS*FF,
    64*HID, HID, RR*HID*HID, RR*HID, RR*HID*HID, RR*HID,
    HID*HID, HID, HID*HID, HID, HID*NCLS, NCLS };
  bool ok = (n_in >= 17) && (out_size == NROWS*NCLS);
  if (ok) for (int i = 0; i < 17; i++) if (in_sizes[i] != expect[i]) { ok = false; break; }
  if (!ok){
    k_fill<<<(NROWS*NCLS+255)/256, 256, 0, stream>>>(out, NROWS*NCLS, 64.0f);
    return;
  }

  const void*  e_src = d_in[1];
  const void*  e_dst = d_in[2];
  const void*  ridx  = d_in[3];
  const void*  rmask = d_in[4];
  const float* nf   = (const float*)d_in[0];
  const float* W_in = (const float*)d_in[5];
  const float* b_in = (const float*)d_in[6];
  const float* W1   = (const float*)d_in[7];
  const float* b1   = (const float*)d_in[8];
  const float* W2   = (const float*)d_in[9];
  const float* b2   = (const float*)d_in[10];
  const float* Wm1  = (const float*)d_in[11];
  const float* bm1  = (const float*)d_in[12];
  const float* Wm2  = (const float*)d_in[13];
  const float* bm2  = (const float*)d_in[14];
  const float* Wm3  = (const float*)d_in[15];
  const float* bm3  = (const float*)d_in[16];

  char* ws = (char*)d_ws;
  size_t off = 0;
  auto take = [&](size_t bytes)->char*{
    char* p = ws + off; off += (bytes + 255) & ~(size_t)255; return p; };

  int*   flags  = (int*)  take(256);
  char*  rgn    =         take(58368000);           // graph-prep + MLP overlays
  bf16*  meanb  = (bf16*) (rgn);                    // MLP overlays
  bf16*  x1     = (bf16*) (rgn + 15360000);
  bf16*  x2     = (bf16*) (rgn + 30720000);
  // graph-prep overlays (dead once k_layer runs)
  int*   ghd    = (int*)  (rgn);                            // [RR*CH][HB] 19,922,944 B
  int*   ghs    = (int*)  (rgn + 19922944);                 // [RR*CH][HB]
  int*   gcurs  = (int*)  (rgn + 19922944);                 // overlays ghs (dead after kg_tot)
  int*   totg   = (int*)  (rgn + 39845888);                 // [RR][HB] 1,245,184 B
  bf16*  h1     = (bf16*) take((size_t)NN*HID*2);
  bf16*  h2     = (bf16*) take((size_t)NN*HID*2);
  int*   rowptr = (int*)  take((size_t)(NRD+1)*4);
  int2*  csrw   = (int2*) take((size_t)RR*EE*8 + 64);
  float* ns     = (float*)take((size_t)NRD*4);
  float* bias   = (float*)take(656*4);
  bf16*  W1p    = (bf16*) take((size_t)2*65536*2);
  bf16*  W2p    = (bf16*) take((size_t)2*65536*2);
  bf16*  Wm1p   = (bf16*) take((size_t)16384*2);
  bf16*  Wm2p   = (bf16*) take((size_t)16384*2);

  if (off > ws_size){
    k_fill<<<(NROWS*NCLS+255)/256, 256, 0, stream>>>(out, NROWS*NCLS, 32.0f);
    return;
  }

  // graph prep: chunked LDS histograms -> in-LDS scan -> atomic-free scatter
  k_sniff   <<<1, 64, 0, stream>>>(rmask, ridx, e_src, flags);
  kg_hist   <<<256, 1024, 0, stream>>>(e_src, e_dst, ghd, ghs, flags);
  kg_tot    <<<(RR*HB+255)/256, 256, 0, stream>>>(ghd, ghs, totg, ns);
  kg_scan   <<<RR, 1024, 0, stream>>>(totg, rowptr);
  kg_curs   <<<(NRD+255)/256, 256, 0, stream>>>(ghd, rowptr, gcurs);
  kg_scatter<<<128, 1024, 0, stream>>>(e_src, e_dst, gcurs, ns, csrw, flags);
  k_bias    <<<1, 128, 0, stream>>>(b_in, b1, b2, bm1, bm2, bm3, bias);

  k_packall<<<(4*65536 + 2*16384 + 255)/256, 256, 0, stream>>>(W1, W2, Wm1, Wm2,
                                                               W1p, W2p, Wm1p, Wm2p);

  // input linear + relu -> h1 (bf16)  [f32 VALU path, r13-r15 proven]
  k_gemm_in<<<NN/4, 128, 0, stream>>>(nf, W_in, bias+0, h1);

  // fused RGCN layers (agg + K=1024 MFMA + bias/relu in one kernel)
  k_layer<<<NN/16, 512, 0, stream>>>(h1, rowptr, (const unsigned long long*)csrw,
                                     W1p, bias+128, h2, 1);
  k_layer<<<NN/16, 512, 0, stream>>>(h2, rowptr, (const unsigned long long*)csrw,
                                     W2p, bias+256, h1, 0);

  // masked mean (graph-phase rgn dead; meanb overlays it)
  k_mean<<<NROWS/4, 256, 0, stream>>>(h1, ridx, rmask, flags, meanb);

  // MLP head
  int gR = (NROWS/16 + 3)/4;   // 938
  k_mfma_out<<<gR, 256, 0, stream>>>(meanb, Wm1p, bias+384, x1, NROWS);
  k_mfma_out<<<gR, 256, 0, stream>>>(x1,    Wm2p, bias+512, x2, NROWS);
  k_last<<<(NROWS*NCLS+255)/256, 256, 0, stream>>>(x2, Wm3, bias+640, out);
}

// Round 9
// 440.448 us; speedup vs baseline: 1.0460x; 1.0460x over previous
//
#include <hip/hip_runtime.h>
#include <hip/hip_bf16.h>

#define NN    38000
#define HID   128
#define RR    8
#define EE    200000
#define NROWS 60000
#define FF    19
#define NCLS  10
#define NRD   (RR*NN)         // 304000
#define HB    38912           // 1024*38, padded bin count (>= NN)
#define CH    8               // chunks per relation
#define CE    (EE/CH)         // 25000 edges per chunk (< 65536 -> u16 counts)

typedef __hip_bfloat16 bf16;
typedef __attribute__((ext_vector_type(8))) short short8;
typedef __attribute__((ext_vector_type(4))) float floatx4;

__device__ __forceinline__ float b2f(bf16 x){ return __bfloat162float(x); }
__device__ __forceinline__ bf16  f2b(float x){ return __float2bfloat16(x); }

__device__ __forceinline__ int geti(const void* a, long long i, int wide){
  return wide ? (int)(((const long long*)a)[i]) : ((const int*)a)[i];
}

__global__ void k_fill(float* out, int n, float v){
  int i = blockIdx.x*256 + threadIdx.x;
  if (i < n) out[i] = v;
}

// r12's proven parallel sniff (1 wave)
__global__ void k_sniff(const void* mask, const void* ridx, const void* esrc, int* flags){
  int lane = threadIdx.x;    // blockDim = 64
  const unsigned short* mu = (const unsigned short*)mask;
  int l3f80e=0, l3f80o=0, lbytehi=0, loddnz=0, lother=0;
  for (int i = lane; i < 4096; i += 64){
    unsigned v = mu[i];
    if (v == 0) continue;
    if (v == 0x3F80){ if (i & 1) l3f80o = 1; else l3f80e = 1; continue; }
    unsigned lo = v & 0xFF, hi = v >> 8;
    int lob = (lo == 0 || lo == 1 || lo == 0xFF);
    int hib = (hi == 0 || hi == 1 || hi == 0xFF);
    if (lob && hib){ if (hi) lbytehi = 1; if (i & 1) loddnz = 1; continue; }
    lother = 1;
  }
  int a3f80e = __any(l3f80e);
  int a3f80o = __any(l3f80o);
  int abytehi = __any(lbytehi);
  int aoddnz = __any(loddnz);
  int aother = __any(lother);
  int mtype = -1;
  if (!aother){
    if (a3f80e && !abytehi && !aoddnz)       mtype = 2;
    else if (a3f80o && !a3f80e && !abytehi)  mtype = 3;
    else if (!a3f80e && !a3f80o){
      if (abytehi || aoddnz) mtype = 1;
      else                   mtype = 0;     // int32 0/1 (actual runtime case)
    }
  }
  const int* es = (const int*)esrc;
  int loddE = 0, lseenE = 0;
  for (int i = lane; i < 512; i += 64){
    if (es[2*i+1] != 0) loddE = 1;
    if (es[2*i] > 1)    lseenE = 1;
  }
  int fE = (!__any(loddE) && __any(lseenE)) ? 1 : 0;
  const int* ri = (const int*)ridx;
  int loddI = 0, lseenI = 0;
  for (int i = lane; i < 512; i += 64){
    if (ri[2*i+1] != 0) loddI = 1;
    if (ri[2*i] > 1)    lseenI = 1;
  }
  int fI = (!__any(loddI) && __any(lseenI)) ? 1 : 0;
  if (lane == 0){ flags[1] = mtype; flags[3] = fE; flags[4] = fI; }
}

// ---- LDS-histogram graph prep (u16 per-chunk counts) ----

// 128 blocks: blocks 0-63 histogram dst (8 rel x 8 chunks), 64-127 histogram src.
__global__ __launch_bounds__(1024) void kg_hist(const void* esrc, const void* edst,
                                                unsigned short* __restrict__ ghd,
                                                unsigned short* __restrict__ ghs,
                                                const int* flags){
  __shared__ int hist[HB];
  int t = threadIdx.x;
  for (int i = t; i < HB; i += 1024) hist[i] = 0;
  __syncthreads();
  int b = blockIdx.x;
  int side = b >> 6;                 // 0: dst, 1: src
  int r = (b >> 3) & 7, c = b & 7;
  int wide = flags[3];
  const void* e = side ? esrc : edst;
  long long base = (long long)r*EE + (long long)c*CE;
  if (!wide){
    const int* p = (const int*)e + base;
    for (int i = t; i < CE; i += 1024) atomicAdd(&hist[p[i]], 1);
  } else {
    const long long* p = (const long long*)e + base;
    for (int i = t; i < CE; i += 1024) atomicAdd(&hist[(int)p[i]], 1);
  }
  __syncthreads();
  unsigned short* out = (side ? ghs : ghd) + (long long)(r*CH + c)*HB;
  for (int i = t; i < HB; i += 1024) out[i] = (unsigned short)hist[i];
}

// wide reduce: per-relation dst totals + ns = rsqrt(outdeg) (folds k_norm)
__global__ void kg_tot(const unsigned short* __restrict__ ghd,
                       const unsigned short* __restrict__ ghs,
                       int* __restrict__ totg, float* __restrict__ ns){
  int i = blockIdx.x*256 + threadIdx.x;   // over RR*HB
  if (i >= RR*HB) return;
  int r = i / HB, bin = i - r*HB;
  int sd = 0, ss = 0;
#pragma unroll
  for (int c = 0; c < CH; c++){
    sd += ghd[(long long)(r*CH+c)*HB + bin];
    ss += ghs[(long long)(r*CH+c)*HB + bin];
  }
  totg[i] = sd;
  if (bin < NN) ns[r*NN + bin] = rsqrtf((float)(ss > 0 ? ss : 1));
}

// per-relation exclusive scan of 38912 bins, fully in LDS -> rowptr
__global__ __launch_bounds__(1024) void kg_scan(const int* __restrict__ totg,
                                                int* __restrict__ rowptr){
  __shared__ int tot[HB];
  __shared__ int wsum[16];
  int t = threadIdx.x, r = blockIdx.x;
  for (int i = t; i < HB; i += 1024) tot[i] = totg[r*HB + i];
  __syncthreads();
  int b0 = t*38;
  int loc[38], s = 0;
#pragma unroll
  for (int j = 0; j < 38; j++){ loc[j] = s; s += tot[b0+j]; }
  int lane = t & 63, w = t >> 6;
  int sc = s;
  for (int off = 1; off < 64; off <<= 1){
    int v = __shfl_up(sc, off);
    if (lane >= off) sc += v;
  }
  if (lane == 63) wsum[w] = sc;
  __syncthreads();
  if (t < 16){
    int v = wsum[t];
    int scw = v;
    for (int off = 1; off < 16; off <<= 1){
      int u = __shfl_up(scw, off);
      if (t >= off) scw += u;
    }
    wsum[t] = scw - v;     // exclusive cross-wave offset
  }
  __syncthreads();
  int base = r*EE + (sc - s) + wsum[w];   // relation base + exclusive prefix
#pragma unroll
  for (int j = 0; j < 38; j++) tot[b0+j] = base + loc[j];
  __syncthreads();
  for (int i = t; i < NN; i += 1024) rowptr[r*NN + i] = tot[i];
  if (r == RR-1 && t == 0) rowptr[NRD] = RR*EE;
}

// wide: per-chunk cursor bases = rowptr + prefix over chunk histograms
__global__ void kg_curs(const unsigned short* __restrict__ ghd,
                        const int* __restrict__ rowptr,
                        int* __restrict__ gcurs){
  int i = blockIdx.x*256 + threadIdx.x;   // over RR*NN
  if (i >= NRD) return;
  int r = i / NN, bin = i - r*NN;
  int p = rowptr[i];
#pragma unroll
  for (int c = 0; c < CH; c++){
    gcurs[(long long)(r*CH+c)*HB + bin] = p;
    p += ghd[(long long)(r*CH+c)*HB + bin];
  }
}

// 64 blocks (8 rel x 8 chunks): LDS cursors, zero global atomics.
// Emits csrw = interleaved (src, ns[src]) 8B pairs so k_layer streams one array.
__global__ __launch_bounds__(1024) void kg_scatter(const void* esrc, const void* edst,
                                                   const int* __restrict__ gcurs,
                                                   const float* __restrict__ ns,
                                                   int2* __restrict__ csrw, const int* flags){
  __shared__ int cur[HB];
  int t = threadIdx.x, b = blockIdx.x;
  int r = b >> 3, c = b & 7;
  const int* g = gcurs + (long long)(r*CH + c)*HB;
  for (int i = t; i < HB; i += 1024) cur[i] = g[i];
  __syncthreads();
  if (b == 0 && t < 8){ int2 z; z.x = 0; z.y = 0; csrw[RR*EE + t] = z; }  // zero pad
  int wide = flags[3];
  const float* nsr = ns + r*NN;
  long long base = (long long)r*EE + (long long)c*CE;
  if (!wide){
    const int* ps = (const int*)esrc + base;
    const int* pd = (const int*)edst + base;
    for (int i = t; i < CE; i += 1024){
      int d = pd[i], s = ps[i];
      int pos = atomicAdd(&cur[d], 1);
      int2 v; v.x = s; v.y = __float_as_int(nsr[s]);
      csrw[pos] = v;
    }
  } else {
    const long long* ps = (const long long*)esrc + base;
    const long long* pd = (const long long*)edst + base;
    for (int i = t; i < CE; i += 1024){
      int d = (int)pd[i], s = (int)ps[i];
      int pos = atomicAdd(&cur[d], 1);
      int2 v; v.x = s; v.y = __float_as_int(nsr[s]);
      csrw[pos] = v;
    }
  }
}

// ---- end graph prep ----

__global__ void k_bias(const float* b_in, const float* b1, const float* b2,
                       const float* bm1, const float* bm2, const float* bm3, float* o){
  int t = threadIdx.x;
  o[t] = b_in[t];
  float s1 = 0.f, s2 = 0.f;
  for (int r = 0; r < RR; r++){ s1 += b1[r*HID+t]; s2 += b2[r*HID+t]; }
  o[128+t] = s1; o[256+t] = s2;
  o[384+t] = bm1[t]; o[512+t] = bm2[t];
  if (t < NCLS) o[640+t] = bm3[t];
}

// one pack kernel: [8][128][128] W1,W2 stacks (K=512 frag order) + Wm1,Wm2 (K=128)
__global__ void k_packall(const float* __restrict__ W1, const float* __restrict__ W2,
                          const float* __restrict__ Wm1, const float* __restrict__ Wm2,
                          bf16* __restrict__ W1p, bf16* __restrict__ W2p,
                          bf16* __restrict__ Wm1p, bf16* __restrict__ Wm2p){
  int idx0 = blockIdx.x*256 + threadIdx.x;
  if (idx0 < 4*65536){
    const float* W = (idx0 < 2*65536) ? W1 : W2;
    bf16* out      = (idx0 < 2*65536) ? W1p : W2p;
    int idx = idx0 & (2*65536 - 1);
    int j = idx & 7;
    int l = (idx >> 3) & 63;
    int t = (idx >> 9) & 127;
    int g = idx >> 16;
    int ktg = t & 15, nt = t >> 4;
    int kglob = ktg*32 + ((l>>4)<<3) + j;
    int rel = kglob >> 7;
    int krow = kglob & 127;
    int n = nt*16 + (l&15);
    out[idx] = f2b(W[((g*4 + rel)*128 + krow)*128 + n]);
  } else if (idx0 < 4*65536 + 2*16384){
    int t2 = idx0 - 4*65536;
    const float* B = (t2 < 16384) ? Wm1 : Wm2;
    bf16* out      = (t2 < 16384) ? Wm1p : Wm2p;
    int idx = t2 & 16383;
    int j  = idx & 7;
    int l  = (idx >> 3) & 63;
    int t  = idx >> 9;          // 0..31
    int kt = t & 3;             // KT=4
    int nt = t >> 2;
    int k = kt*32 + ((l>>4)<<3) + j;
    int n = nt*16 + (l&15);
    out[idx] = f2b(B[k*128 + n]);
  }
}

// input linear + relu (f32 VALU, K=64) -> h1 bf16  [r13-r15 proven, restored]
__global__ void k_gemm_in(const float* __restrict__ A, const float* __restrict__ B,
                          const float* bias, bf16* __restrict__ out){
  int row0 = blockIdx.x * 4;
  int col = threadIdx.x;
  float a0=0.f, a1=0.f, a2=0.f, a3=0.f;
  for (int k = 0; k < 64; k++){
    float bv = B[k*HID + col];
    a0 += A[(long long)(row0+0)*64 + k] * bv;
    a1 += A[(long long)(row0+1)*64 + k] * bv;
    a2 += A[(long long)(row0+2)*64 + k] * bv;
    a3 += A[(long long)(row0+3)*64 + k] * bv;
  }
  float bb = bias[col];
  out[(long long)(row0+0)*HID + col] = f2b(fmaxf(a0 + bb, 0.f));
  out[(long long)(row0+1)*HID + col] = f2b(fmaxf(a1 + bb, 0.f));
  out[(long long)(row0+2)*HID + col] = f2b(fmaxf(a2 + bb, 0.f));
  out[(long long)(row0+3)*HID + col] = f2b(fmaxf(a3 + bb, 0.f));
}

// ---- k_layer: fused agg + MFMA, row-pipelined phase 1 (r8 structure) ----
#define LOADW(Q, base_) \
  Q##0 = cw[(base_)+0]; Q##1 = cw[(base_)+1]; Q##2 = cw[(base_)+2]; Q##3 = cw[(base_)+3]; \
  Q##4 = cw[(base_)+4]; Q##5 = cw[(base_)+5]; Q##6 = cw[(base_)+6]; Q##7 = cw[(base_)+7];

#define GATHW(P, Q) \
  P##0 = hv[(long long)(int)Q##0*64 + lane]; \
  P##1 = hv[(long long)(int)Q##1*64 + lane]; \
  P##2 = hv[(long long)(int)Q##2*64 + lane]; \
  P##3 = hv[(long long)(int)Q##3*64 + lane]; \
  P##4 = hv[(long long)(int)Q##4*64 + lane]; \
  P##5 = hv[(long long)(int)Q##5*64 + lane]; \
  P##6 = hv[(long long)(int)Q##6*64 + lane]; \
  P##7 = hv[(long long)(int)Q##7*64 + lane];

#define ACCE(Qv, Pv, cond) { \
  float wk_ = (cond) ? __int_as_float((int)((Qv) >> 32)) : 0.f; \
  acc0 += wk_ * __uint_as_float((Pv) << 16); \
  acc1 += wk_ * __uint_as_float((Pv) & 0xffff0000u); }

#define ROWBODY(i, QC, PC, QN, PN) { \
  int b_ = __builtin_amdgcn_readfirstlane(__shfl(rp, (i))); \
  int e_ = __builtin_amdgcn_readfirstlane(__shfl(rp, (i)+1)); \
  LOADW(QN, e_)                       /* next row's window (begin = e_) */ \
  GATHW(PN, QN)                       /* issue next row's gathers */ \
  float acc0 = 0.f, acc1 = 0.f; \
  ACCE(QC##0, PC##0, b_+0 < e_) \
  ACCE(QC##1, PC##1, b_+1 < e_) \
  ACCE(QC##2, PC##2, b_+2 < e_) \
  ACCE(QC##3, PC##3, b_+3 < e_) \
  ACCE(QC##4, PC##4, b_+4 < e_) \
  ACCE(QC##5, PC##5, b_+5 < e_) \
  ACCE(QC##6, PC##6, b_+6 < e_) \
  ACCE(QC##7, PC##7, b_+7 < e_) \
  for (int j = b_ + 8; j < e_; j += 8){      /* slow path: deg > 8 (~9% rows) */ \
    unsigned long long q0 = cw[j],   q1 = cw[j+1], q2 = cw[j+2], q3 = cw[j+3]; \
    unsigned long long q4 = cw[j+4], q5 = cw[j+5], q6 = cw[j+6], q7 = cw[j+7]; \
    unsigned p0 = hv[(long long)(int)q0*64 + lane]; \
    unsigned p1 = hv[(long long)(int)q1*64 + lane]; \
    unsigned p2 = hv[(long long)(int)q2*64 + lane]; \
    unsigned p3 = hv[(long long)(int)q3*64 + lane]; \
    unsigned p4 = hv[(long long)(int)q4*64 + lane]; \
    unsigned p5 = hv[(long long)(int)q5*64 + lane]; \
    unsigned p6 = hv[(long long)(int)q6*64 + lane]; \
    unsigned p7 = hv[(long long)(int)q7*64 + lane]; \
    ACCE(q0, p0, 1) \
    ACCE(q1, p1, j+1 < e_) \
    ACCE(q2, p2, j+2 < e_) \
    ACCE(q3, p3, j+3 < e_) \
    ACCE(q4, p4, j+4 < e_) \
    ACCE(q5, p5, j+5 < e_) \
    ACCE(q6, p6, j+6 < e_) \
    ACCE(q7, p7, j+7 < e_) \
  } \
  int deg = e_ - b_; \
  float nd = rsqrtf((float)(deg > 0 ? deg : 1)); \
  bf16 o0 = f2b(acc0 * nd), o1 = f2b(acc1 * nd); \
  unsigned ov = ((unsigned)(*(unsigned short*)&o1) << 16) | (*(unsigned short*)&o0); \
  int addr = (w << 12) + ((i) << 8) + (lane << 2); \
  addr ^= (((i) & 7) << 4); \
  *(unsigned*)(lds + addr) = ov; }

__global__ __launch_bounds__(512) void k_layer(const bf16* __restrict__ h,
                                               const int* __restrict__ rowptr,
                                               const unsigned long long* __restrict__ cw,
                                               const bf16* __restrict__ Bp,
                                               const float* __restrict__ bias,
                                               bf16* __restrict__ hout, int relu){
  __shared__ char lds[8*16*256];     // 8 relation tiles of [16 rows][128 bf16], swizzled
  int w = threadIdx.x >> 6;          // wave id = relation
  int lane = threadIdx.x & 63;
  int d0 = blockIdx.x << 4;
  const unsigned* hv = (const unsigned*)h;

  // 17 row boundaries, one coalesced read
  int rp = 0;
  if (lane < 17) rp = rowptr[w*NN + d0 + lane];

  unsigned long long qa0,qa1,qa2,qa3,qa4,qa5,qa6,qa7;
  unsigned long long qb0,qb1,qb2,qb3,qb4,qb5,qb6,qb7;
  unsigned pa0,pa1,pa2,pa3,pa4,pa5,pa6,pa7;
  unsigned pb0,pb1,pb2,pb3,pb4,pb5,pb6,pb7;

  // prologue: row 0's window + gathers
  {
    int b0_ = __builtin_amdgcn_readfirstlane(__shfl(rp, 0));
    LOADW(qa, b0_)
    GATHW(pa, qa)
  }
  ROWBODY( 0, qa, pa, qb, pb)
  ROWBODY( 1, qb, pb, qa, pa)
  ROWBODY( 2, qa, pa, qb, pb)
  ROWBODY( 3, qb, pb, qa, pa)
  ROWBODY( 4, qa, pa, qb, pb)
  ROWBODY( 5, qb, pb, qa, pa)
  ROWBODY( 6, qa, pa, qb, pb)
  ROWBODY( 7, qb, pb, qa, pa)
  ROWBODY( 8, qa, pa, qb, pb)
  ROWBODY( 9, qb, pb, qa, pa)
  ROWBODY(10, qa, pa, qb, pb)
  ROWBODY(11, qb, pb, qa, pa)
  ROWBODY(12, qa, pa, qb, pb)
  ROWBODY(13, qb, pb, qa, pa)
  ROWBODY(14, qa, pa, qb, pb)
  ROWBODY(15, qb, pb, qa, pa)
  __syncthreads();

  // phase 2: K=1024 MFMA, wave w -> output cols [16w, 16w+16)
  floatx4 acc = (floatx4){0.f,0.f,0.f,0.f};
  int row = lane & 15;
  int kb = (lane >> 4) << 4;                      // (lane>>4)*8 elems * 2B
#pragma unroll
  for (int rel = 0; rel < 8; rel++){
    int half = rel >> 2;
    const bf16* bp = Bp + half*65536 + lane*8 + (w*16 + (rel & 3)*4)*512;
#pragma unroll
    for (int ktl = 0; ktl < 4; ktl++){
      // full unswizzled offset FIRST, then XOR (r3 carry-through-swizzle fix)
      int off = (row << 8) + ktl*64 + kb;
      off ^= ((row & 7) << 4);
      short8 a = *(const short8*)(lds + (rel << 12) + off);
      short8 b = *(const short8*)(bp + ktl*512);
      acc = __builtin_amdgcn_mfma_f32_16x16x32_bf16(a, b, acc, 0, 0, 0);
    }
  }
  int col = w*16 + (lane & 15);
  int row0 = d0 + ((lane >> 4) << 2);
  float bb = bias[col];
#pragma unroll
  for (int v = 0; v < 4; v++){
    float x = acc[v] + bb;
    if (relu) x = fmaxf(x, 0.f);
    hout[(long long)(row0 + v)*HID + col] = f2b(x);
  }
}

// ---- k_head: fused masked-mean + MLP (Wm1,Wm2 MFMA) + final f32 layer ----
// 256 thr (4 waves), 16 rows/block. Phase A: wave wv means rows wv*4..wv*4+3
// (r2-proven ballot gather) -> swizzled LDS tile A. Phase B1/B2: 4-wave-split
// k_mfma_out (wave wv -> nt {2wv,2wv+1}), bf16 rounding identical to the old
// k_mfma_out. Phase C: k_last's f32 dot from LDS, same k-order -> bit-identical.
__global__ __launch_bounds__(256) void k_head(const bf16* __restrict__ h,
                                              const void* ridx, const void* rmask,
                                              const int* __restrict__ flags,
                                              const bf16* __restrict__ Wm1p,
                                              const bf16* __restrict__ Wm2p,
                                              const float* __restrict__ Wm3,
                                              const float* __restrict__ bias,
                                              float* __restrict__ out){
  __shared__ char ldsA[16*256];
  __shared__ char ldsB[16*256];
  int wv = threadIdx.x >> 6;
  int lane = threadIdx.x & 63;
  int r0 = blockIdx.x << 4;
  int mt = flags[1];
  int wide = flags[4];
  const int* m4            = (const int*)rmask;
  const unsigned char* m1  = (const unsigned char*)rmask;
  const unsigned short* m2 = (const unsigned short*)rmask;
  const unsigned int* mw   = (const unsigned int*)rmask;
  const unsigned* hv = (const unsigned*)h;

  // phase A: means
  for (int rr = 0; rr < 4; rr++){
    int tr = wv*4 + rr;
    int row = r0 + tr;
    int on = 0, idxl = 0;
    if (lane < FF){
      long long i = (long long)row*FF + lane;
      if      (mt == 1) on = (m1[i] != 0);
      else if (mt == 2) on = (m2[i] != 0);
      else if (mt == 3) on = (mw[i] != 0);
      else              on = (m4[i] != 0);
      if (on) idxl = geti(ridx, i, wide);
    }
    unsigned long long bal = __ballot(on);
    float cnt = (float)__popcll(bal);
    float acc0 = 0.f, acc1 = 0.f;
#pragma unroll
    for (int j = 0; j < FF; j++){
      int s = __shfl(idxl, j);
      float wgt = (float)((bal >> j) & 1ull);
      unsigned pv = hv[(long long)s*64 + lane];
      acc0 += wgt * __uint_as_float(pv << 16);
      acc1 += wgt * __uint_as_float(pv & 0xffff0000u);
    }
    float inv = 1.f / fmaxf(cnt, 1.f);
    bf16 o0 = f2b(acc0 * inv), o1 = f2b(acc1 * inv);
    unsigned ov = ((unsigned)(*(unsigned short*)&o1) << 16) | (*(unsigned short*)&o0);
    int addr = (tr << 8) + (lane << 2);
    addr ^= ((tr & 7) << 4);
    *(unsigned*)(ldsA + addr) = ov;
  }
  __syncthreads();

  int arow = lane & 15;
  int kb = (lane >> 4) << 4;
  int colB = lane & 15;
  int rowQ = (lane >> 4) << 2;

  // phase B1: x1 = relu(mean @ Wm1 + bm1) -> ldsB
  {
    floatx4 accA = (floatx4){0.f,0.f,0.f,0.f};
    floatx4 accB = (floatx4){0.f,0.f,0.f,0.f};
    const bf16* bp = Wm1p + lane*8;
#pragma unroll
    for (int kt = 0; kt < 4; kt++){
      int off = (arow << 8) + kt*64 + kb;
      off ^= ((arow & 7) << 4);
      short8 a = *(const short8*)(ldsA + off);
      short8 b0 = *(const short8*)(bp + ((wv*2+0)*4 + kt)*512);
      short8 b1 = *(const short8*)(bp + ((wv*2+1)*4 + kt)*512);
      accA = __builtin_amdgcn_mfma_f32_16x16x32_bf16(a, b0, accA, 0, 0, 0);
      accB = __builtin_amdgcn_mfma_f32_16x16x32_bf16(a, b1, accB, 0, 0, 0);
    }
#pragma unroll
    for (int ntl = 0; ntl < 2; ntl++){
      int col = (wv*2 + ntl)*16 + colB;
      float bb = bias[384 + col];
#pragma unroll
      for (int v = 0; v < 4; v++){
        float x = ((ntl == 0) ? accA[v] : accB[v]) + bb;
        bf16 xv = f2b(fmaxf(x, 0.f));
        int rowi = rowQ + v;
        int addr = (rowi << 8) + col*2;
        addr ^= ((rowi & 7) << 4);
        *(unsigned short*)(ldsB + addr) = *(unsigned short*)&xv;
      }
    }
  }
  __syncthreads();

  // phase B2: x2 = relu(x1 @ Wm2 + bm2) -> ldsA
  {
    floatx4 accA = (floatx4){0.f,0.f,0.f,0.f};
    floatx4 accB = (floatx4){0.f,0.f,0.f,0.f};
    const bf16* bp = Wm2p + lane*8;
#pragma unroll
    for (int kt = 0; kt < 4; kt++){
      int off = (arow << 8) + kt*64 + kb;
      off ^= ((arow & 7) << 4);
      short8 a = *(const short8*)(ldsB + off);
      short8 b0 = *(const short8*)(bp + ((wv*2+0)*4 + kt)*512);
      short8 b1 = *(const short8*)(bp + ((wv*2+1)*4 + kt)*512);
      accA = __builtin_amdgcn_mfma_f32_16x16x32_bf16(a, b0, accA, 0, 0, 0);
      accB = __builtin_amdgcn_mfma_f32_16x16x32_bf16(a, b1, accB, 0, 0, 0);
    }
#pragma unroll
    for (int ntl = 0; ntl < 2; ntl++){
      int col = (wv*2 + ntl)*16 + colB;
      float bb = bias[512 + col];
#pragma unroll
      for (int v = 0; v < 4; v++){
        float x = ((ntl == 0) ? accA[v] : accB[v]) + bb;
        bf16 xv = f2b(fmaxf(x, 0.f));
        int rowi = rowQ + v;
        int addr = (rowi << 8) + col*2;
        addr ^= ((rowi & 7) << 4);
        *(unsigned short*)(ldsA + addr) = *(unsigned short*)&xv;
      }
    }
  }
  __syncthreads();

  // phase C: out = x2 @ Wm3 + bm3 (f32, same k-order as old k_last)
  for (int t = threadIdx.x; t < 16*NCLS; t += 256){
    int tr = t / NCLS, col = t - tr*NCLS;
    float acc = bias[640 + col];
    for (int k = 0; k < HID; k++){
      int addr = (tr << 8) + k*2;
      addr ^= ((tr & 7) << 4);
      unsigned short uv = *(const unsigned short*)(ldsA + addr);
      acc += b2f(*(bf16*)&uv) * Wm3[k*NCLS + col];
    }
    out[(long long)(r0 + tr)*NCLS + col] = acc;
  }
}

extern "C" void kernel_launch(void* const* d_in, const int* in_sizes, int n_in,
                              void* d_out, int out_size, void* d_ws, size_t ws_size,
                              hipStream_t stream){
  float* out = (float*)d_out;

  static const int expect[17] = {
    NN*64, RR*EE, RR*EE, NROWS*FF, NROWS*FF,
    64*HID, HID, RR*HID*HID, RR*HID, RR*HID*HID, RR*HID,
    HID*HID, HID, HID*HID, HID, HID*NCLS, NCLS };
  bool ok = (n_in >= 17) && (out_size == NROWS*NCLS);
  if (ok) for (int i = 0; i < 17; i++) if (in_sizes[i] != expect[i]) { ok = false; break; }
  if (!ok){
    k_fill<<<(NROWS*NCLS+255)/256, 256, 0, stream>>>(out, NROWS*NCLS, 64.0f);
    return;
  }

  const void*  e_src = d_in[1];
  const void*  e_dst = d_in[2];
  const void*  ridx  = d_in[3];
  const void*  rmask = d_in[4];
  const float* nf   = (const float*)d_in[0];
  const float* W_in = (const float*)d_in[5];
  const float* b_in = (const float*)d_in[6];
  const float* W1   = (const float*)d_in[7];
  const float* b1   = (const float*)d_in[8];
  const float* W2   = (const float*)d_in[9];
  const float* b2   = (const float*)d_in[10];
  const float* Wm1  = (const float*)d_in[11];
  const float* bm1  = (const float*)d_in[12];
  const float* Wm2  = (const float*)d_in[13];
  const float* bm2  = (const float*)d_in[14];
  const float* Wm3  = (const float*)d_in[15];
  const float* bm3  = (const float*)d_in[16];

  char* ws = (char*)d_ws;
  size_t off = 0;
  auto take = [&](size_t bytes)->char*{
    char* p = ws + off; off += (bytes + 255) & ~(size_t)255; return p; };

  int*   flags  = (int*)  take(256);
  char*  rgn    =         take(58368000);           // graph-prep overlays
  unsigned short* ghd = (unsigned short*)(rgn);             // [RR*CH][HB] u16 = 4,980,736 B
  unsigned short* ghs = (unsigned short*)(rgn + 4980736);   // [RR*CH][HB] u16
  int*   gcurs  = (int*)  (rgn +  9961472);                 // [RR*CH][HB] i32 = 9,961,472 B
  int*   totg   = (int*)  (rgn + 19922944);                 // [RR][HB] i32 1,245,184 B
  bf16*  h1     = (bf16*) take((size_t)NN*HID*2);
  bf16*  h2     = (bf16*) take((size_t)NN*HID*2);
  int*   rowptr = (int*)  take((size_t)(NRD+1)*4);
  int2*  csrw   = (int2*) take((size_t)RR*EE*8 + 64);
  float* ns     = (float*)take((size_t)NRD*4);
  float* bias   = (float*)take(656*4);
  bf16*  W1p    = (bf16*) take((size_t)2*65536*2);
  bf16*  W2p    = (bf16*) take((size_t)2*65536*2);
  bf16*  Wm1p   = (bf16*) take((size_t)16384*2);
  bf16*  Wm2p   = (bf16*) take((size_t)16384*2);

  if (off > ws_size){
    k_fill<<<(NROWS*NCLS+255)/256, 256, 0, stream>>>(out, NROWS*NCLS, 32.0f);
    return;
  }

  // graph prep: chunked LDS histograms (u16) -> in-LDS scan -> atomic-free scatter
  k_sniff   <<<1, 64, 0, stream>>>(rmask, ridx, e_src, flags);
  kg_hist   <<<128, 1024, 0, stream>>>(e_src, e_dst, ghd, ghs, flags);
  kg_tot    <<<(RR*HB+255)/256, 256, 0, stream>>>(ghd, ghs, totg, ns);
  kg_scan   <<<RR, 1024, 0, stream>>>(totg, rowptr);
  kg_curs   <<<(NRD+255)/256, 256, 0, stream>>>(ghd, rowptr, gcurs);
  kg_scatter<<<64, 1024, 0, stream>>>(e_src, e_dst, gcurs, ns, csrw, flags);
  k_bias    <<<1, 128, 0, stream>>>(b_in, b1, b2, bm1, bm2, bm3, bias);

  k_packall<<<(4*65536 + 2*16384 + 255)/256, 256, 0, stream>>>(W1, W2, Wm1, Wm2,
                                                               W1p, W2p, Wm1p, Wm2p);

  // input linear + relu -> h1 (bf16)
  k_gemm_in<<<NN/4, 128, 0, stream>>>(nf, W_in, bias+0, h1);

  // fused RGCN layers (agg + K=1024 MFMA + bias/relu in one kernel)
  k_layer<<<NN/16, 512, 0, stream>>>(h1, rowptr, (const unsigned long long*)csrw,
                                     W1p, bias+128, h2, 1);
  k_layer<<<NN/16, 512, 0, stream>>>(h2, rowptr, (const unsigned long long*)csrw,
                                     W2p, bias+256, h1, 0);

  // fused head: mean -> Wm1 -> Wm2 -> Wm3 (one kernel, all intermediates in LDS)
  k_head<<<NROWS/16, 256, 0, stream>>>(h1, ridx, rmask, flags, Wm1p, Wm2p, Wm3, bias, out);
}

// Round 10
// 412.145 us; speedup vs baseline: 1.1179x; 1.0687x over previous
//
#include <hip/hip_runtime.h>
#include <hip/hip_bf16.h>

#define NN    38000
#define HID   128
#define RR    8
#define EE    200000
#define NROWS 60000
#define FF    19
#define NCLS  10
#define NRD   (RR*NN)         // 304000
#define HB    38912           // 1024*38, padded bin count (>= NN)
#define CH    16              // chunks per relation
#define CE    (EE/CH)         // 12500 edges per chunk (< 65536 -> u16 counts)

typedef __hip_bfloat16 bf16;
typedef __attribute__((ext_vector_type(8))) short short8;
typedef __attribute__((ext_vector_type(4))) float floatx4;
typedef __attribute__((ext_vector_type(2))) float float2v;

__device__ __forceinline__ float b2f(bf16 x){ return __bfloat162float(x); }
__device__ __forceinline__ bf16  f2b(float x){ return __float2bfloat16(x); }

__device__ __forceinline__ int geti(const void* a, long long i, int wide){
  return wide ? (int)(((const long long*)a)[i]) : ((const int*)a)[i];
}

__global__ void k_fill(float* out, int n, float v){
  int i = blockIdx.x*256 + threadIdx.x;
  if (i < n) out[i] = v;
}

// r12's proven parallel sniff (1 wave)
__global__ void k_sniff(const void* mask, const void* ridx, const void* esrc, int* flags){
  int lane = threadIdx.x;    // blockDim = 64
  const unsigned short* mu = (const unsigned short*)mask;
  int l3f80e=0, l3f80o=0, lbytehi=0, loddnz=0, lother=0;
  for (int i = lane; i < 4096; i += 64){
    unsigned v = mu[i];
    if (v == 0) continue;
    if (v == 0x3F80){ if (i & 1) l3f80o = 1; else l3f80e = 1; continue; }
    unsigned lo = v & 0xFF, hi = v >> 8;
    int lob = (lo == 0 || lo == 1 || lo == 0xFF);
    int hib = (hi == 0 || hi == 1 || hi == 0xFF);
    if (lob && hib){ if (hi) lbytehi = 1; if (i & 1) loddnz = 1; continue; }
    lother = 1;
  }
  int a3f80e = __any(l3f80e);
  int a3f80o = __any(l3f80o);
  int abytehi = __any(lbytehi);
  int aoddnz = __any(loddnz);
  int aother = __any(lother);
  int mtype = -1;
  if (!aother){
    if (a3f80e && !abytehi && !aoddnz)       mtype = 2;
    else if (a3f80o && !a3f80e && !abytehi)  mtype = 3;
    else if (!a3f80e && !a3f80o){
      if (abytehi || aoddnz) mtype = 1;
      else                   mtype = 0;     // int32 0/1 (actual runtime case)
    }
  }
  const int* es = (const int*)esrc;
  int loddE = 0, lseenE = 0;
  for (int i = lane; i < 512; i += 64){
    if (es[2*i+1] != 0) loddE = 1;
    if (es[2*i] > 1)    lseenE = 1;
  }
  int fE = (!__any(loddE) && __any(lseenE)) ? 1 : 0;
  const int* ri = (const int*)ridx;
  int loddI = 0, lseenI = 0;
  for (int i = lane; i < 512; i += 64){
    if (ri[2*i+1] != 0) loddI = 1;
    if (ri[2*i] > 1)    lseenI = 1;
  }
  int fI = (!__any(loddI) && __any(lseenI)) ? 1 : 0;
  if (lane == 0){ flags[1] = mtype; flags[3] = fE; flags[4] = fI; }
}

// ---- LDS-histogram graph prep (u16 per-chunk counts, CH=16 for full-width) ----

// 256 blocks: blocks 0-127 histogram dst (8 rel x 16 chunks), 128-255 histogram src.
__global__ __launch_bounds__(1024) void kg_hist(const void* esrc, const void* edst,
                                                unsigned short* __restrict__ ghd,
                                                unsigned short* __restrict__ ghs,
                                                const int* flags){
  __shared__ int hist[HB];
  int t = threadIdx.x;
  for (int i = t; i < HB; i += 1024) hist[i] = 0;
  __syncthreads();
  int b = blockIdx.x;
  int side = b >> 7;                 // 0: dst, 1: src
  int r = (b >> 4) & 7, c = b & 15;
  int wide = flags[3];
  const void* e = side ? esrc : edst;
  long long base = (long long)r*EE + (long long)c*CE;
  if (!wide){
    const int* p = (const int*)e + base;
    for (int i = t; i < CE; i += 1024) atomicAdd(&hist[p[i]], 1);
  } else {
    const long long* p = (const long long*)e + base;
    for (int i = t; i < CE; i += 1024) atomicAdd(&hist[(int)p[i]], 1);
  }
  __syncthreads();
  unsigned short* out = (side ? ghs : ghd) + (long long)(r*CH + c)*HB;
  for (int i = t; i < HB; i += 1024) out[i] = (unsigned short)hist[i];
}

// wide reduce: per-relation dst totals + ns = rsqrt(outdeg) (folds k_norm)
__global__ void kg_tot(const unsigned short* __restrict__ ghd,
                       const unsigned short* __restrict__ ghs,
                       int* __restrict__ totg, float* __restrict__ ns){
  int i = blockIdx.x*256 + threadIdx.x;   // over RR*HB
  if (i >= RR*HB) return;
  int r = i / HB, bin = i - r*HB;
  int sd = 0, ss = 0;
#pragma unroll
  for (int c = 0; c < CH; c++){
    sd += ghd[(long long)(r*CH+c)*HB + bin];
    ss += ghs[(long long)(r*CH+c)*HB + bin];
  }
  totg[i] = sd;
  if (bin < NN) ns[r*NN + bin] = rsqrtf((float)(ss > 0 ? ss : 1));
}

// per-relation exclusive scan of 38912 bins, fully in LDS -> rowptr
__global__ __launch_bounds__(1024) void kg_scan(const int* __restrict__ totg,
                                                int* __restrict__ rowptr){
  __shared__ int tot[HB];
  __shared__ int wsum[16];
  int t = threadIdx.x, r = blockIdx.x;
  for (int i = t; i < HB; i += 1024) tot[i] = totg[r*HB + i];
  __syncthreads();
  int b0 = t*38;
  int loc[38], s = 0;
#pragma unroll
  for (int j = 0; j < 38; j++){ loc[j] = s; s += tot[b0+j]; }
  int lane = t & 63, w = t >> 6;
  int sc = s;
  for (int off = 1; off < 64; off <<= 1){
    int v = __shfl_up(sc, off);
    if (lane >= off) sc += v;
  }
  if (lane == 63) wsum[w] = sc;
  __syncthreads();
  if (t < 16){
    int v = wsum[t];
    int scw = v;
    for (int off = 1; off < 16; off <<= 1){
      int u = __shfl_up(scw, off);
      if (t >= off) scw += u;
    }
    wsum[t] = scw - v;     // exclusive cross-wave offset
  }
  __syncthreads();
  int base = r*EE + (sc - s) + wsum[w];   // relation base + exclusive prefix
#pragma unroll
  for (int j = 0; j < 38; j++) tot[b0+j] = base + loc[j];
  __syncthreads();
  for (int i = t; i < NN; i += 1024) rowptr[r*NN + i] = tot[i];
  if (r == RR-1 && t == 0) rowptr[NRD] = RR*EE;
}

// wide: per-chunk cursor bases = rowptr + prefix over chunk histograms
__global__ void kg_curs(const unsigned short* __restrict__ ghd,
                        const int* __restrict__ rowptr,
                        int* __restrict__ gcurs){
  int i = blockIdx.x*256 + threadIdx.x;   // over RR*NN
  if (i >= NRD) return;
  int r = i / NN, bin = i - r*NN;
  int p = rowptr[i];
#pragma unroll
  for (int c = 0; c < CH; c++){
    gcurs[(long long)(r*CH+c)*HB + bin] = p;
    p += ghd[(long long)(r*CH+c)*HB + bin];
  }
}

// 128 blocks (8 rel x 16 chunks): LDS cursors, zero global atomics.
// Emits csrw = interleaved (src*64, ns[src]) 8B pairs (pre-scaled word offset).
__global__ __launch_bounds__(1024) void kg_scatter(const void* esrc, const void* edst,
                                                   const int* __restrict__ gcurs,
                                                   const float* __restrict__ ns,
                                                   int2* __restrict__ csrw, const int* flags){
  __shared__ int cur[HB];
  int t = threadIdx.x, b = blockIdx.x;
  int r = b >> 4, c = b & 15;
  const int* g = gcurs + (long long)(r*CH + c)*HB;
  for (int i = t; i < HB; i += 1024) cur[i] = g[i];
  __syncthreads();
  if (b == 0 && t < 8){ int2 z; z.x = 0; z.y = 0; csrw[RR*EE + t] = z; }  // zero pad
  int wide = flags[3];
  const float* nsr = ns + r*NN;
  long long base = (long long)r*EE + (long long)c*CE;
  if (!wide){
    const int* ps = (const int*)esrc + base;
    const int* pd = (const int*)edst + base;
    for (int i = t; i < CE; i += 1024){
      int d = pd[i], s = ps[i];
      int pos = atomicAdd(&cur[d], 1);
      int2 v; v.x = s << 6; v.y = __float_as_int(nsr[s]);
      csrw[pos] = v;
    }
  } else {
    const long long* ps = (const long long*)esrc + base;
    const long long* pd = (const long long*)edst + base;
    for (int i = t; i < CE; i += 1024){
      int d = (int)pd[i], s = (int)ps[i];
      int pos = atomicAdd(&cur[d], 1);
      int2 v; v.x = s << 6; v.y = __float_as_int(nsr[s]);
      csrw[pos] = v;
    }
  }
}

// ---- end graph prep ----

__global__ void k_bias(const float* b_in, const float* b1, const float* b2,
                       const float* bm1, const float* bm2, const float* bm3, float* o){
  int t = threadIdx.x;
  o[t] = b_in[t];
  float s1 = 0.f, s2 = 0.f;
  for (int r = 0; r < RR; r++){ s1 += b1[r*HID+t]; s2 += b2[r*HID+t]; }
  o[128+t] = s1; o[256+t] = s2;
  o[384+t] = bm1[t]; o[512+t] = bm2[t];
  if (t < NCLS) o[640+t] = bm3[t];
}

// one pack kernel: [8][128][128] W1,W2 stacks (K=512 frag order) + Wm1,Wm2 (K=128)
__global__ void k_packall(const float* __restrict__ W1, const float* __restrict__ W2,
                          const float* __restrict__ Wm1, const float* __restrict__ Wm2,
                          bf16* __restrict__ W1p, bf16* __restrict__ W2p,
                          bf16* __restrict__ Wm1p, bf16* __restrict__ Wm2p){
  int idx0 = blockIdx.x*256 + threadIdx.x;
  if (idx0 < 4*65536){
    const float* W = (idx0 < 2*65536) ? W1 : W2;
    bf16* out      = (idx0 < 2*65536) ? W1p : W2p;
    int idx = idx0 & (2*65536 - 1);
    int j = idx & 7;
    int l = (idx >> 3) & 63;
    int t = (idx >> 9) & 127;
    int g = idx >> 16;
    int ktg = t & 15, nt = t >> 4;
    int kglob = ktg*32 + ((l>>4)<<3) + j;
    int rel = kglob >> 7;
    int krow = kglob & 127;
    int n = nt*16 + (l&15);
    out[idx] = f2b(W[((g*4 + rel)*128 + krow)*128 + n]);
  } else if (idx0 < 4*65536 + 2*16384){
    int t2 = idx0 - 4*65536;
    const float* B = (t2 < 16384) ? Wm1 : Wm2;
    bf16* out      = (t2 < 16384) ? Wm1p : Wm2p;
    int idx = t2 & 16383;
    int j  = idx & 7;
    int l  = (idx >> 3) & 63;
    int t  = idx >> 9;          // 0..31
    int kt = t & 3;             // KT=4
    int nt = t >> 2;
    int k = kt*32 + ((l>>4)<<3) + j;
    int n = nt*16 + (l&15);
    out[idx] = f2b(B[k*128 + n]);
  }
}

// input linear + relu (f32 VALU, K=64) -> h1 bf16  [r13-r15 proven, restored]
__global__ void k_gemm_in(const float* __restrict__ A, const float* __restrict__ B,
                          const float* bias, bf16* __restrict__ out){
  int row0 = blockIdx.x * 4;
  int col = threadIdx.x;
  float a0=0.f, a1=0.f, a2=0.f, a3=0.f;
  for (int k = 0; k < 64; k++){
    float bv = B[k*HID + col];
    a0 += A[(long long)(row0+0)*64 + k] * bv;
    a1 += A[(long long)(row0+1)*64 + k] * bv;
    a2 += A[(long long)(row0+2)*64 + k] * bv;
    a3 += A[(long long)(row0+3)*64 + k] * bv;
  }
  float bb = bias[col];
  out[(long long)(row0+0)*HID + col] = f2b(fmaxf(a0 + bb, 0.f));
  out[(long long)(row0+1)*HID + col] = f2b(fmaxf(a1 + bb, 0.f));
  out[(long long)(row0+2)*HID + col] = f2b(fmaxf(a2 + bb, 0.f));
  out[(long long)(row0+3)*HID + col] = f2b(fmaxf(a3 + bb, 0.f));
}

// ---- k_layer: fused agg + MFMA, row-pipelined phase 1 (r8 structure) ----
// csrw.x is pre-scaled (src*64 words) -> gather addr has no per-edge scale op.
// Accumulate is a float2 vector FMA -> v_pk_fma_f32 (same fma precision/order).
#define LOADW(Q, base_) \
  Q##0 = cw[(base_)+0]; Q##1 = cw[(base_)+1]; Q##2 = cw[(base_)+2]; Q##3 = cw[(base_)+3]; \
  Q##4 = cw[(base_)+4]; Q##5 = cw[(base_)+5]; Q##6 = cw[(base_)+6]; Q##7 = cw[(base_)+7];

#define GATHW(P, Q) \
  P##0 = hv[(int)Q##0 + lane]; \
  P##1 = hv[(int)Q##1 + lane]; \
  P##2 = hv[(int)Q##2 + lane]; \
  P##3 = hv[(int)Q##3 + lane]; \
  P##4 = hv[(int)Q##4 + lane]; \
  P##5 = hv[(int)Q##5 + lane]; \
  P##6 = hv[(int)Q##6 + lane]; \
  P##7 = hv[(int)Q##7 + lane];

#define ACCE(Qv, Pv, cond) { \
  float wk_ = (cond) ? __int_as_float((int)((Qv) >> 32)) : 0.f; \
  float2v xv_; \
  xv_.x = __uint_as_float((Pv) << 16); \
  xv_.y = __uint_as_float((Pv) & 0xffff0000u); \
  acc2 += (float2v){wk_, wk_} * xv_; }

#define ROWBODY(i, QC, PC, QN, PN) { \
  int b_ = __builtin_amdgcn_readfirstlane(__shfl(rp, (i))); \
  int e_ = __builtin_amdgcn_readfirstlane(__shfl(rp, (i)+1)); \
  LOADW(QN, e_)                       /* next row's window (begin = e_) */ \
  GATHW(PN, QN)                       /* issue next row's gathers */ \
  float2v acc2 = (float2v){0.f, 0.f}; \
  ACCE(QC##0, PC##0, b_+0 < e_) \
  ACCE(QC##1, PC##1, b_+1 < e_) \
  ACCE(QC##2, PC##2, b_+2 < e_) \
  ACCE(QC##3, PC##3, b_+3 < e_) \
  ACCE(QC##4, PC##4, b_+4 < e_) \
  ACCE(QC##5, PC##5, b_+5 < e_) \
  ACCE(QC##6, PC##6, b_+6 < e_) \
  ACCE(QC##7, PC##7, b_+7 < e_) \
  for (int j = b_ + 8; j < e_; j += 8){      /* slow path: deg > 8 (~9% rows) */ \
    unsigned long long q0 = cw[j],   q1 = cw[j+1], q2 = cw[j+2], q3 = cw[j+3]; \
    unsigned long long q4 = cw[j+4], q5 = cw[j+5], q6 = cw[j+6], q7 = cw[j+7]; \
    unsigned p0 = hv[(int)q0 + lane]; \
    unsigned p1 = hv[(int)q1 + lane]; \
    unsigned p2 = hv[(int)q2 + lane]; \
    unsigned p3 = hv[(int)q3 + lane]; \
    unsigned p4 = hv[(int)q4 + lane]; \
    unsigned p5 = hv[(int)q5 + lane]; \
    unsigned p6 = hv[(int)q6 + lane]; \
    unsigned p7 = hv[(int)q7 + lane]; \
    ACCE(q0, p0, 1) \
    ACCE(q1, p1, j+1 < e_) \
    ACCE(q2, p2, j+2 < e_) \
    ACCE(q3, p3, j+3 < e_) \
    ACCE(q4, p4, j+4 < e_) \
    ACCE(q5, p5, j+5 < e_) \
    ACCE(q6, p6, j+6 < e_) \
    ACCE(q7, p7, j+7 < e_) \
  } \
  int deg = e_ - b_; \
  float nd = rsqrtf((float)(deg > 0 ? deg : 1)); \
  bf16 o0 = f2b(acc2.x * nd), o1 = f2b(acc2.y * nd); \
  unsigned ov = ((unsigned)(*(unsigned short*)&o1) << 16) | (*(unsigned short*)&o0); \
  int addr = (w << 12) + ((i) << 8) + (lane << 2); \
  addr ^= (((i) & 7) << 4); \
  *(unsigned*)(lds + addr) = ov; }

__global__ __launch_bounds__(512) void k_layer(const bf16* __restrict__ h,
                                               const int* __restrict__ rowptr,
                                               const unsigned long long* __restrict__ cw,
                                               const bf16* __restrict__ Bp,
                                               const float* __restrict__ bias,
                                               bf16* __restrict__ hout, int relu){
  __shared__ char lds[8*16*256];     // 8 relation tiles of [16 rows][128 bf16], swizzled
  int w = threadIdx.x >> 6;          // wave id = relation
  int lane = threadIdx.x & 63;
  int d0 = blockIdx.x << 4;
  const unsigned* hv = (const unsigned*)h;

  // 17 row boundaries, one coalesced read
  int rp = 0;
  if (lane < 17) rp = rowptr[w*NN + d0 + lane];

  unsigned long long qa0,qa1,qa2,qa3,qa4,qa5,qa6,qa7;
  unsigned long long qb0,qb1,qb2,qb3,qb4,qb5,qb6,qb7;
  unsigned pa0,pa1,pa2,pa3,pa4,pa5,pa6,pa7;
  unsigned pb0,pb1,pb2,pb3,pb4,pb5,pb6,pb7;

  // prologue: row 0's window + gathers
  {
    int b0_ = __builtin_amdgcn_readfirstlane(__shfl(rp, 0));
    LOADW(qa, b0_)
    GATHW(pa, qa)
  }
  ROWBODY( 0, qa, pa, qb, pb)
  ROWBODY( 1, qb, pb, qa, pa)
  ROWBODY( 2, qa, pa, qb, pb)
  ROWBODY( 3, qb, pb, qa, pa)
  ROWBODY( 4, qa, pa, qb, pb)
  ROWBODY( 5, qb, pb, qa, pa)
  ROWBODY( 6, qa, pa, qb, pb)
  ROWBODY( 7, qb, pb, qa, pa)
  ROWBODY( 8, qa, pa, qb, pb)
  ROWBODY( 9, qb, pb, qa, pa)
  ROWBODY(10, qa, pa, qb, pb)
  ROWBODY(11, qb, pb, qa, pa)
  ROWBODY(12, qa, pa, qb, pb)
  ROWBODY(13, qb, pb, qa, pa)
  ROWBODY(14, qa, pa, qb, pb)
  ROWBODY(15, qb, pb, qa, pa)
  __syncthreads();

  // phase 2: K=1024 MFMA, wave w -> output cols [16w, 16w+16)
  floatx4 acc = (floatx4){0.f,0.f,0.f,0.f};
  int row = lane & 15;
  int kb = (lane >> 4) << 4;                      // (lane>>4)*8 elems * 2B
#pragma unroll
  for (int rel = 0; rel < 8; rel++){
    int half = rel >> 2;
    const bf16* bp = Bp + half*65536 + lane*8 + (w*16 + (rel & 3)*4)*512;
#pragma unroll
    for (int ktl = 0; ktl < 4; ktl++){
      // full unswizzled offset FIRST, then XOR (r3 carry-through-swizzle fix)
      int off = (row << 8) + ktl*64 + kb;
      off ^= ((row & 7) << 4);
      short8 a = *(const short8*)(lds + (rel << 12) + off);
      short8 b = *(const short8*)(bp + ktl*512);
      acc = __builtin_amdgcn_mfma_f32_16x16x32_bf16(a, b, acc, 0, 0, 0);
    }
  }
  int col = w*16 + (lane & 15);
  int row0 = d0 + ((lane >> 4) << 2);
  float bb = bias[col];
#pragma unroll
  for (int v = 0; v < 4; v++){
    float x = acc[v] + bb;
    if (relu) x = fmaxf(x, 0.f);
    hout[(long long)(row0 + v)*HID + col] = f2b(x);
  }
}

// ---- k_head: fused masked-mean + MLP (Wm1,Wm2 MFMA) + final f32 layer ----
__global__ __launch_bounds__(256) void k_head(const bf16* __restrict__ h,
                                              const void* ridx, const void* rmask,
                                              const int* __restrict__ flags,
                                              const bf16* __restrict__ Wm1p,
                                              const bf16* __restrict__ Wm2p,
                                              const float* __restrict__ Wm3,
                                              const float* __restrict__ bias,
                                              float* __restrict__ out){
  __shared__ char ldsA[16*256];
  __shared__ char ldsB[16*256];
  int wv = threadIdx.x >> 6;
  int lane = threadIdx.x & 63;
  int r0 = blockIdx.x << 4;
  int mt = flags[1];
  int wide = flags[4];
  const int* m4            = (const int*)rmask;
  const unsigned char* m1  = (const unsigned char*)rmask;
  const unsigned short* m2 = (const unsigned short*)rmask;
  const unsigned int* mw   = (const unsigned int*)rmask;
  const unsigned* hv = (const unsigned*)h;

  // phase A: means
  for (int rr = 0; rr < 4; rr++){
    int tr = wv*4 + rr;
    int row = r0 + tr;
    int on = 0, idxl = 0;
    if (lane < FF){
      long long i = (long long)row*FF + lane;
      if      (mt == 1) on = (m1[i] != 0);
      else if (mt == 2) on = (m2[i] != 0);
      else if (mt == 3) on = (mw[i] != 0);
      else              on = (m4[i] != 0);
      if (on) idxl = geti(ridx, i, wide);
    }
    unsigned long long bal = __ballot(on);
    float cnt = (float)__popcll(bal);
    float acc0 = 0.f, acc1 = 0.f;
#pragma unroll
    for (int j = 0; j < FF; j++){
      int s = __shfl(idxl, j);
      float wgt = (float)((bal >> j) & 1ull);
      unsigned pv = hv[(long long)s*64 + lane];
      acc0 += wgt * __uint_as_float(pv << 16);
      acc1 += wgt * __uint_as_float(pv & 0xffff0000u);
    }
    float inv = 1.f / fmaxf(cnt, 1.f);
    bf16 o0 = f2b(acc0 * inv), o1 = f2b(acc1 * inv);
    unsigned ov = ((unsigned)(*(unsigned short*)&o1) << 16) | (*(unsigned short*)&o0);
    int addr = (tr << 8) + (lane << 2);
    addr ^= ((tr & 7) << 4);
    *(unsigned*)(ldsA + addr) = ov;
  }
  __syncthreads();

  int arow = lane & 15;
  int kb = (lane >> 4) << 4;
  int colB = lane & 15;
  int rowQ = (lane >> 4) << 2;

  // phase B1: x1 = relu(mean @ Wm1 + bm1) -> ldsB
  {
    floatx4 accA = (floatx4){0.f,0.f,0.f,0.f};
    floatx4 accB = (floatx4){0.f,0.f,0.f,0.f};
    const bf16* bp = Wm1p + lane*8;
#pragma unroll
    for (int kt = 0; kt < 4; kt++){
      int off = (arow << 8) + kt*64 + kb;
      off ^= ((arow & 7) << 4);
      short8 a = *(const short8*)(ldsA + off);
      short8 b0 = *(const short8*)(bp + ((wv*2+0)*4 + kt)*512);
      short8 b1 = *(const short8*)(bp + ((wv*2+1)*4 + kt)*512);
      accA = __builtin_amdgcn_mfma_f32_16x16x32_bf16(a, b0, accA, 0, 0, 0);
      accB = __builtin_amdgcn_mfma_f32_16x16x32_bf16(a, b1, accB, 0, 0, 0);
    }
#pragma unroll
    for (int ntl = 0; ntl < 2; ntl++){
      int col = (wv*2 + ntl)*16 + colB;
      float bb = bias[384 + col];
#pragma unroll
      for (int v = 0; v < 4; v++){
        float x = ((ntl == 0) ? accA[v] : accB[v]) + bb;
        bf16 xv = f2b(fmaxf(x, 0.f));
        int rowi = rowQ + v;
        int addr = (rowi << 8) + col*2;
        addr ^= ((rowi & 7) << 4);
        *(unsigned short*)(ldsB + addr) = *(unsigned short*)&xv;
      }
    }
  }
  __syncthreads();

  // phase B2: x2 = relu(x1 @ Wm2 + bm2) -> ldsA
  {
    floatx4 accA = (floatx4){0.f,0.f,0.f,0.f};
    floatx4 accB = (floatx4){0.f,0.f,0.f,0.f};
    const bf16* bp = Wm2p + lane*8;
#pragma unroll
    for (int kt = 0; kt < 4; kt++){
      int off = (arow << 8) + kt*64 + kb;
      off ^= ((arow & 7) << 4);
      short8 a = *(const short8*)(ldsB + off);
      short8 b0 = *(const short8*)(bp + ((wv*2+0)*4 + kt)*512);
      short8 b1 = *(const short8*)(bp + ((wv*2+1)*4 + kt)*512);
      accA = __builtin_amdgcn_mfma_f32_16x16x32_bf16(a, b0, accA, 0, 0, 0);
      accB = __builtin_amdgcn_mfma_f32_16x16x32_bf16(a, b1, accB, 0, 0, 0);
    }
#pragma unroll
    for (int ntl = 0; ntl < 2; ntl++){
      int col = (wv*2 + ntl)*16 + colB;
      float bb = bias[512 + col];
#pragma unroll
      for (int v = 0; v < 4; v++){
        float x = ((ntl == 0) ? accA[v] : accB[v]) + bb;
        bf16 xv = f2b(fmaxf(x, 0.f));
        int rowi = rowQ + v;
        int addr = (rowi << 8) + col*2;
        addr ^= ((rowi & 7) << 4);
        *(unsigned short*)(ldsA + addr) = *(unsigned short*)&xv;
      }
    }
  }
  __syncthreads();

  // phase C: out = x2 @ Wm3 + bm3 (f32, same k-order as old k_last)
  for (int t = threadIdx.x; t < 16*NCLS; t += 256){
    int tr = t / NCLS, col = t - tr*NCLS;
    float acc = bias[640 + col];
    for (int k = 0; k < HID; k++){
      int addr = (tr << 8) + k*2;
      addr ^= ((tr & 7) << 4);
      unsigned short uv = *(const unsigned short*)(ldsA + addr);
      acc += b2f(*(bf16*)&uv) * Wm3[k*NCLS + col];
    }
    out[(long long)(r0 + tr)*NCLS + col] = acc;
  }
}

extern "C" void kernel_launch(void* const* d_in, const int* in_sizes, int n_in,
                              void* d_out, int out_size, void* d_ws, size_t ws_size,
                              hipStream_t stream){
  float* out = (float*)d_out;

  static const int expect[17] = {
    NN*64, RR*EE, RR*EE, NROWS*FF, NROWS*FF,
    64*HID, HID, RR*HID*HID, RR*HID, RR*HID*HID, RR*HID,
    HID*HID, HID, HID*HID, HID, HID*NCLS, NCLS };
  bool ok = (n_in >= 17) && (out_size == NROWS*NCLS);
  if (ok) for (int i = 0; i < 17; i++) if (in_sizes[i] != expect[i]) { ok = false; break; }
  if (!ok){
    k_fill<<<(NROWS*NCLS+255)/256, 256, 0, stream>>>(out, NROWS*NCLS, 64.0f);
    return;
  }

  const void*  e_src = d_in[1];
  const void*  e_dst = d_in[2];
  const void*  ridx  = d_in[3];
  const void*  rmask = d_in[4];
  const float* nf   = (const float*)d_in[0];
  const float* W_in = (const float*)d_in[5];
  const float* b_in = (const float*)d_in[6];
  const float* W1   = (const float*)d_in[7];
  const float* b1   = (const float*)d_in[8];
  const float* W2   = (const float*)d_in[9];
  const float* b2   = (const float*)d_in[10];
  const float* Wm1  = (const float*)d_in[11];
  const float* bm1  = (const float*)d_in[12];
  const float* Wm2  = (const float*)d_in[13];
  const float* bm2  = (const float*)d_in[14];
  const float* Wm3  = (const float*)d_in[15];
  const float* bm3  = (const float*)d_in[16];

  char* ws = (char*)d_ws;
  size_t off = 0;
  auto take = [&](size_t bytes)->char*{
    char* p = ws + off; off += (bytes + 255) & ~(size_t)255; return p; };

  int*   flags  = (int*)  take(256);
  char*  rgn    =         take(58368000);           // graph-prep overlays
  unsigned short* ghd = (unsigned short*)(rgn);             // [RR*CH][HB] u16 = 9,961,472 B
  unsigned short* ghs = (unsigned short*)(rgn + 9961472);   // [RR*CH][HB] u16
  int*   gcurs  = (int*)  (rgn + 19922944);                 // [RR*CH][HB] i32 = 19,922,944 B
  int*   totg   = (int*)  (rgn + 39845888);                 // [RR][HB] i32 1,245,184 B
  bf16*  h1     = (bf16*) take((size_t)NN*HID*2);
  bf16*  h2     = (bf16*) take((size_t)NN*HID*2);
  int*   rowptr = (int*)  take((size_t)(NRD+1)*4);
  int2*  csrw   = (int2*) take((size_t)RR*EE*8 + 64);
  float* ns     = (float*)take((size_t)NRD*4);
  float* bias   = (float*)take(656*4);
  bf16*  W1p    = (bf16*) take((size_t)2*65536*2);
  bf16*  W2p    = (bf16*) take((size_t)2*65536*2);
  bf16*  Wm1p   = (bf16*) take((size_t)16384*2);
  bf16*  Wm2p   = (bf16*) take((size_t)16384*2);

  if (off > ws_size){
    k_fill<<<(NROWS*NCLS+255)/256, 256, 0, stream>>>(out, NROWS*NCLS, 32.0f);
    return;
  }

  // graph prep: chunked LDS histograms (u16, CH=16) -> in-LDS scan -> atomic-free scatter
  k_sniff   <<<1, 64, 0, stream>>>(rmask, ridx, e_src, flags);
  kg_hist   <<<256, 1024, 0, stream>>>(e_src, e_dst, ghd, ghs, flags);
  kg_tot    <<<(RR*HB+255)/256, 256, 0, stream>>>(ghd, ghs, totg, ns);
  kg_scan   <<<RR, 1024, 0, stream>>>(totg, rowptr);
  kg_curs   <<<(NRD+255)/256, 256, 0, stream>>>(ghd, rowptr, gcurs);
  kg_scatter<<<128, 1024, 0, stream>>>(e_src, e_dst, gcurs, ns, csrw, flags);
  k_bias    <<<1, 128, 0, stream>>>(b_in, b1, b2, bm1, bm2, bm3, bias);

  k_packall<<<(4*65536 + 2*16384 + 255)/256, 256, 0, stream>>>(W1, W2, Wm1, Wm2,
                                                               W1p, W2p, Wm1p, Wm2p);

  // input linear + relu -> h1 (bf16)
  k_gemm_in<<<NN/4, 128, 0, stream>>>(nf, W_in, bias+0, h1);

  // fused RGCN layers (agg + K=1024 MFMA + bias/relu in one kernel)
  k_layer<<<NN/16, 512, 0, stream>>>(h1, rowptr, (const unsigned long long*)csrw,
                                     W1p, bias+128, h2, 1);
  k_layer<<<NN/16, 512, 0, stream>>>(h2, rowptr, (const unsigned long long*)csrw,
                                     W2p, bias+256, h1, 0);

  // fused head: mean -> Wm1 -> Wm2 -> Wm3 (one kernel, all intermediates in LDS)
  k_head<<<NROWS/16, 256, 0, stream>>>(h1, ridx, rmask, flags, Wm1p, Wm2p, Wm3, bias, out);
}